// Round 1
// 2092.866 us; speedup vs baseline: 1.4308x; 1.4308x over previous
//
#include <hip/hip_runtime.h>
#include <cstdint>
#include <cstddef>

using bf16x8 = __attribute__((ext_vector_type(8))) short;
using f32x4  = __attribute__((ext_vector_type(4))) float;

#define HDIM 768
#define H4DIM 3072
#define NDIM 64
#define SEQ 2048
#define MROWS 4096
#define VOCAB 32000
#define KTAPS 128

__device__ __forceinline__ unsigned short f2bf(float f) {
    union { float f; unsigned u; } v; v.f = f;
    unsigned r = v.u + 0x7fffu + ((v.u >> 16) & 1u);
    return (unsigned short)(r >> 16);
}

// async global->LDS, 16B per lane (wave-uniform LDS base + lane*16: LDS layout must be linear)
__device__ __forceinline__ void gload_lds16(const void* g, void* l) {
    __builtin_amdgcn_global_load_lds(
        (const __attribute__((address_space(1))) unsigned int*)g,
        (__attribute__((address_space(3))) unsigned int*)l, 16, 0, 0);
}

// ---------------- embed cast f32 -> bf16 (whole [V,H] matrix) ----------------
__global__ __launch_bounds__(256) void cast_embed_kernel(const float* __restrict__ src,
                                                         unsigned short* __restrict__ dst) {
    size_t g = (size_t)blockIdx.x * 256 + threadIdx.x;   // one float4 per thread
    const float4 v = *(const float4*)(src + g * 4);
    ushort4 u;
    u.x = f2bf(v.x); u.y = f2bf(v.y); u.z = f2bf(v.z); u.w = f2bf(v.w);
    *(ushort4*)(dst + g * 4) = u;
}

// ---------------- embedding gather ----------------
__global__ __launch_bounds__(192) void gather_kernel(const int* __restrict__ tokens,
                                                     const float* __restrict__ embed,
                                                     float* __restrict__ h) {
    int row = blockIdx.x;                       // 0..4095
    int tok = tokens[row];
    const float4 v = *(const float4*)(embed + (size_t)tok * HDIM + threadIdx.x * 4);
    *(float4*)(h + (size_t)row * HDIM + threadIdx.x * 4) = v;
}

// ---------------- layernorm over H=768, f32 out (feeds conv) ----------------
__global__ __launch_bounds__(256) void ln_kernel(const float* __restrict__ in,
                                                 float* __restrict__ out,
                                                 const float* __restrict__ w,
                                                 const float* __restrict__ b) {
    int row = blockIdx.x, tid = threadIdx.x;
    const float* x = in + (size_t)row * HDIM;
    float x0 = x[tid], x1 = x[tid + 256], x2 = x[tid + 512];
    float s = x0 + x1 + x2;
    float s2 = x0 * x0 + x1 * x1 + x2 * x2;
    for (int o = 32; o; o >>= 1) { s += __shfl_down(s, o); s2 += __shfl_down(s2, o); }
    __shared__ float red[8];
    int lane = tid & 63, wv = tid >> 6;
    if (lane == 0) { red[wv] = s; red[4 + wv] = s2; }
    __syncthreads();
    s  = red[0] + red[1] + red[2] + red[3];
    s2 = red[4] + red[5] + red[6] + red[7];
    float m   = s * (1.0f / HDIM);
    float var = s2 * (1.0f / HDIM) - m * m;
    float inv = 1.0f / sqrtf(var + 1e-5f);
    float* o_ = out + (size_t)row * HDIM;
    o_[tid]       = (x0 - m) * inv * w[tid]       + b[tid];
    o_[tid + 256] = (x1 - m) * inv * w[tid + 256] + b[tid + 256];
    o_[tid + 512] = (x2 - m) * inv * w[tid + 512] + b[tid + 512];
}

// ---------------- layernorm, bf16 out (feeds GEMM A-side; same rounding the old
// GEMM staging applied, so numerics are unchanged) ----------------
__global__ __launch_bounds__(256) void ln_bf16_kernel(const float* __restrict__ in,
                                                      unsigned short* __restrict__ out,
                                                      const float* __restrict__ w,
                                                      const float* __restrict__ b) {
    int row = blockIdx.x, tid = threadIdx.x;
    const float* x = in + (size_t)row * HDIM;
    float x0 = x[tid], x1 = x[tid + 256], x2 = x[tid + 512];
    float s = x0 + x1 + x2;
    float s2 = x0 * x0 + x1 * x1 + x2 * x2;
    for (int o = 32; o; o >>= 1) { s += __shfl_down(s, o); s2 += __shfl_down(s2, o); }
    __shared__ float red[8];
    int lane = tid & 63, wv = tid >> 6;
    if (lane == 0) { red[wv] = s; red[4 + wv] = s2; }
    __syncthreads();
    s  = red[0] + red[1] + red[2] + red[3];
    s2 = red[4] + red[5] + red[6] + red[7];
    float m   = s * (1.0f / HDIM);
    float var = s2 * (1.0f / HDIM) - m * m;
    float inv = 1.0f / sqrtf(var + 1e-5f);
    unsigned short* o_ = out + (size_t)row * HDIM;
    o_[tid]       = f2bf((x0 - m) * inv * w[tid]       + b[tid]);
    o_[tid + 256] = f2bf((x1 - m) * inv * w[tid + 256] + b[tid + 256]);
    o_[tid + 512] = f2bf((x2 - m) * inv * w[tid + 512] + b[tid + 512]);
}

// ---------------- S4D conv-kernel generation: Kk[d][h] = dt_h * sum_n C*B*exp(-dt_h*A_n*d) ----
__global__ __launch_bounds__(128) void s4d_gen_kernel(const float* __restrict__ A_log,  // [N]
                                                      const float* __restrict__ Bm,     // [H,N]
                                                      const float* __restrict__ Cm,     // [H,N]
                                                      const float* __restrict__ log_dt, // [H]
                                                      float* __restrict__ Kk) {         // [KTAPS,H]
    int hh = blockIdx.x;          // 0..767
    int d  = threadIdx.x;         // 0..127
    __shared__ float cb[NDIM], ae[NDIM];
    if (threadIdx.x < NDIM) {
        cb[threadIdx.x] = Bm[(size_t)hh * NDIM + threadIdx.x] * Cm[(size_t)hh * NDIM + threadIdx.x];
        ae[threadIdx.x] = expf(A_log[threadIdx.x]);
    }
    __syncthreads();
    float dt = expf(log_dt[hh]);
    float fd = (float)d;
    float s = 0.f;
    #pragma unroll 8
    for (int n = 0; n < NDIM; ++n) s += cb[n] * expf(-dt * ae[n] * fd);
    Kk[(size_t)d * HDIM + hh] = dt * s;
}

// ---------------- causal depthwise conv + residual: h += conv(x) ----------------
// 4 rows per thread, f32x4 over channels; sliding register window for x.
// Loads are all address-independent (shift is register renaming under unroll),
// so there is no serial load chain; boundary handled by zero-fill (branch is
// block-uniform: t0 is the same for all 192 threads).
__global__ __launch_bounds__(192) void conv_resid_kernel(const float* __restrict__ x,
                                                         const float* __restrict__ Kk,
                                                         float* __restrict__ h) {
    int blk = blockIdx.x;            // 4-row group: global rows blk*4 .. +3
    int hv  = threadIdx.x;           // 0..191 (float4 over H)
    int r0  = blk * 4;
    int t0  = r0 & (SEQ - 1);        // sequence-local time of row 0 (SEQ%4==0 so group never spans seqs)
    const float* xp = x + (size_t)r0 * HDIM + hv * 4;
    const float* kp = Kk + hv * 4;
    f32x4 w0 = *(const f32x4*)(xp);
    f32x4 w1 = *(const f32x4*)(xp + HDIM);
    f32x4 w2 = *(const f32x4*)(xp + 2 * HDIM);
    f32x4 w3 = *(const f32x4*)(xp + 3 * HDIM);
    f32x4 a0 = {}, a1 = {}, a2 = {}, a3 = {};
    #pragma unroll 4
    for (int d = 0; d < KTAPS; ++d) {
        f32x4 kv = *(const f32x4*)(kp + (ptrdiff_t)d * HDIM);
        a0 += kv * w0; a1 += kv * w1; a2 += kv * w2; a3 += kv * w3;
        w3 = w2; w2 = w1; w1 = w0;
        f32x4 nw = {};
        if (t0 - 1 - d >= 0) nw = *(const f32x4*)(xp - (ptrdiff_t)(d + 1) * HDIM);
        w0 = nw;
    }
    float* hp = h + (size_t)r0 * HDIM + hv * 4;
    *(f32x4*)(hp)            = *(const f32x4*)(hp)            + a0;
    *(f32x4*)(hp + HDIM)     = *(const f32x4*)(hp + HDIM)     + a1;
    *(f32x4*)(hp + 2 * HDIM) = *(const f32x4*)(hp + 2 * HDIM) + a2;
    *(f32x4*)(hp + 3 * HDIM) = *(const f32x4*)(hp + 3 * HDIM) + a3;
}

// ---------------- transpose + cast: src f32 [R][C] -> dst bf16 [C][R] ----------------
__global__ __launch_bounds__(256) void transpose_cast_kernel(const float* __restrict__ src,
                                                             unsigned short* __restrict__ dst,
                                                             int R, int C) {
    __shared__ float tile[32][33];
    int tx = threadIdx.x, ty = threadIdx.y;     // (32, 8)
    int gx = blockIdx.x * 32, gy = blockIdx.y * 32;
    #pragma unroll
    for (int i = 0; i < 4; ++i) {
        int ry = ty + i * 8;
        tile[ry][tx] = src[(size_t)(gy + ry) * C + gx + tx];
    }
    __syncthreads();
    #pragma unroll
    for (int i = 0; i < 4; ++i) {
        int ry = ty + i * 8;
        dst[(size_t)(gx + ry) * R + gy + tx] = f2bf(tile[tx][ry]);
    }
}

// ---------------- m97-structure bf16 MFMA GEMM ----------------
// C[M,N] = A[M,K](bf16) @ Bt[N,K](bf16)^T
// 128x128 tile, BK=32, 4 waves in 2x2, each wave 64x64 via 4x4 of 16x16x32 MFMAs.
// Staging: global_load_lds width-16, linear LDS [128][32] (dest must be linear:
// wave-uniform base + lane*16). Known conflict cost of the linear layout is the
// accepted m97 tradeoff (~874-912 TF at 4096^3 in learn_hip).
// EPI: 0 = plain f32 store, 1 = gelu(x+bias) -> bf16 store, 2 = x+bias+resid -> f32
template <int EPI>
__global__ __launch_bounds__(256) void gemm128_kernel(const unsigned short* __restrict__ A,
                                                      const unsigned short* __restrict__ Bt,
                                                      void* __restrict__ Cout,
                                                      const float* __restrict__ bias,
                                                      const float* __restrict__ resid,
                                                      int N, int K, int swz) {
    __shared__ unsigned short As[128 * 32];
    __shared__ unsigned short Bs[128 * 32];
    int tid  = threadIdx.x;
    int lane = tid & 63, wave = tid >> 6;
    int wm = (wave >> 1) * 64, wn = (wave & 1) * 64;

    int bx = blockIdx.x, by = blockIdx.y;
    if (swz) {  // XCD-chunked remap (bijective: nwg % 8 == 0 for all our grids)
        int nwg  = gridDim.x * gridDim.y;
        int flat = by * gridDim.x + bx;
        int s    = (flat & 7) * (nwg >> 3) + (flat >> 3);
        bx = s % gridDim.x; by = s / gridDim.x;
    }
    size_t bm = by, bn = bx;
    const unsigned short* Ab = A  + bm * 128 * (size_t)K;
    const unsigned short* Bb = Bt + bn * 128 * (size_t)K;

    f32x4 acc[4][4] = {};

    for (int k0 = 0; k0 < K; k0 += 32) {
        __syncthreads();                       // previous compute done before overwrite
        #pragma unroll
        for (int i = 0; i < 2; ++i) {
            int qq  = tid + i * 256;           // 0..511 : 16B chunk id, linear in LDS
            int row = qq >> 2, kq = (qq & 3) * 8;
            gload_lds16(Ab + (size_t)row * K + k0 + kq, &As[qq * 8]);
            gload_lds16(Bb + (size_t)row * K + k0 + kq, &Bs[qq * 8]);
        }
        __syncthreads();                       // compiler drains vmcnt before barrier
        int mr = lane & 15, kf = (lane >> 4) * 8;
        bf16x8 af[4], bf[4];
        #pragma unroll
        for (int m = 0; m < 4; ++m) af[m] = *(const bf16x8*)(&As[(wm + m * 16 + mr) * 32 + kf]);
        #pragma unroll
        for (int n = 0; n < 4; ++n) bf[n] = *(const bf16x8*)(&Bs[(wn + n * 16 + mr) * 32 + kf]);
        #pragma unroll
        for (int m = 0; m < 4; ++m)
            #pragma unroll
            for (int n = 0; n < 4; ++n)
                acc[m][n] = __builtin_amdgcn_mfma_f32_16x16x32_bf16(af[m], bf[n], acc[m][n], 0, 0, 0);
    }

    // C/D layout: col = lane&15, row = (lane>>4)*4 + reg  (verified mapping)
    int mr = lane & 15, rq = (lane >> 4) * 4;
    #pragma unroll
    for (int m = 0; m < 4; ++m) {
        #pragma unroll
        for (int n = 0; n < 4; ++n) {
            int col = (int)bn * 128 + wn + n * 16 + mr;
            #pragma unroll
            for (int r = 0; r < 4; ++r) {
                int row = (int)bm * 128 + wm + m * 16 + rq + r;
                float v = acc[m][n][r];
                if (EPI == 1) {
                    v += bias[col];
                    v = 0.5f * v * (1.0f + erff(v * 0.70710678118654752f));
                    ((unsigned short*)Cout)[(size_t)row * N + col] = f2bf(v);
                } else if (EPI == 2) {
                    v += bias[col] + resid[(size_t)row * N + col];
                    ((float*)Cout)[(size_t)row * N + col] = v;
                } else {
                    ((float*)Cout)[(size_t)row * N + col] = v;
                }
            }
        }
    }
}

extern "C" void kernel_launch(void* const* d_in, const int* in_sizes, int n_in,
                              void* d_out, int out_size, void* d_ws, size_t ws_size,
                              hipStream_t stream) {
    const int*   tokens = (const int*)  d_in[0];
    const float* embed  = (const float*)d_in[1];
    const float* ln1_w  = (const float*)d_in[2];
    const float* ln1_b  = (const float*)d_in[3];
    const float* A_log  = (const float*)d_in[4];
    const float* Bm     = (const float*)d_in[5];
    const float* Cm     = (const float*)d_in[6];
    const float* log_dt = (const float*)d_in[7];
    const float* ln2_w  = (const float*)d_in[8];
    const float* ln2_b  = (const float*)d_in[9];
    const float* W1     = (const float*)d_in[10];
    const float* b1     = (const float*)d_in[11];
    const float* W2     = (const float*)d_in[12];
    const float* b2     = (const float*)d_in[13];
    const float* lnf_w  = (const float*)d_in[14];
    const float* lnf_b  = (const float*)d_in[15];
    float* out = (float*)d_out;

    // workspace layout (all segments 16B-aligned; total ~116 MB)
    float* h   = (float*)d_ws;                                   // 4096*768 f32
    float* xb  = h  + (size_t)MROWS * HDIM;                      // 4096*768 f32 (LN1 out, conv in)
    float* Kk  = xb + (size_t)MROWS * HDIM;                      // 128*768 f32
    unsigned short* xbf = (unsigned short*)(Kk + (size_t)KTAPS * HDIM);  // 4096*768 bf16 (LN2/LNF out)
    unsigned short* Gbf = xbf + (size_t)MROWS * HDIM;            // 4096*3072 bf16 (gelu out)
    unsigned short* w1t = Gbf + (size_t)MROWS * H4DIM;           // 3072*768 bf16
    unsigned short* w2t = w1t + (size_t)H4DIM * HDIM;            // 768*3072 bf16
    unsigned short* ebf = w2t + (size_t)H4DIM * HDIM;            // 32000*768 bf16

    // embed -> bf16 [V][H]  (B^T layout for the head GEMM)
    cast_embed_kernel<<<(VOCAB * HDIM) / 1024, 256, 0, stream>>>(embed, ebf);
    // h = embed[tokens]
    gather_kernel<<<MROWS, 192, 0, stream>>>(tokens, embed, h);

    for (int l = 0; l < 6; ++l) {
        // S4D conv taps for this layer
        s4d_gen_kernel<<<HDIM, 128, 0, stream>>>(A_log + l * NDIM,
                                                 Bm + (size_t)l * HDIM * NDIM,
                                                 Cm + (size_t)l * HDIM * NDIM,
                                                 log_dt + l * HDIM, Kk);
        // x = LN1(h)  (f32, feeds conv)
        ln_kernel<<<MROWS, 256, 0, stream>>>(h, xb, ln1_w + l * HDIM, ln1_b + l * HDIM);
        // h += conv(x)
        conv_resid_kernel<<<MROWS / 4, 192, 0, stream>>>(xb, Kk, h);
        // z = LN2(h) -> bf16 (GEMM1 A-side)
        ln_bf16_kernel<<<MROWS, 256, 0, stream>>>(h, xbf, ln2_w + l * HDIM, ln2_b + l * HDIM);
        // weight transposes+casts: W1[H,4H] -> [4H][H] bf16 ; W2[4H,H] -> [H][4H] bf16
        transpose_cast_kernel<<<dim3(H4DIM / 32, HDIM / 32), dim3(32, 8), 0, stream>>>(
            W1 + (size_t)l * HDIM * H4DIM, w1t, HDIM, H4DIM);
        transpose_cast_kernel<<<dim3(HDIM / 32, H4DIM / 32), dim3(32, 8), 0, stream>>>(
            W2 + (size_t)l * HDIM * H4DIM, w2t, H4DIM, HDIM);
        // G = gelu(z @ W1 + b1) -> bf16
        gemm128_kernel<1><<<dim3(H4DIM / 128, MROWS / 128), 256, 0, stream>>>(
            xbf, w1t, Gbf, b1 + l * H4DIM, nullptr, H4DIM, HDIM, 0);
        // h = h + (G @ W2 + b2)
        gemm128_kernel<2><<<dim3(HDIM / 128, MROWS / 128), 256, 0, stream>>>(
            Gbf, w2t, h, b2 + l * HDIM, h, HDIM, H4DIM, 0);
    }

    // hf = LNF(h) -> bf16
    ln_bf16_kernel<<<MROWS, 256, 0, stream>>>(h, xbf, lnf_w, lnf_b);
    // logits = hf @ embed^T   (8000 blocks, HBM-heavy -> XCD swizzle on)
    gemm128_kernel<0><<<dim3(VOCAB / 128, MROWS / 128), 256, 0, stream>>>(
        xbf, ebf, out, nullptr, nullptr, VOCAB, HDIM, 1);
}